// Round 1
// 357.646 us; speedup vs baseline: 1.4664x; 1.4664x over previous
//
#include <hip/hip_runtime.h>

#define KSTATES 64

__device__ __forceinline__ float wave_max64(float v) {
#pragma unroll
  for (int off = 32; off; off >>= 1) v = fmaxf(v, __shfl_xor(v, off, 64));
  return v;
}

__device__ __forceinline__ float wave_sum64(float v) {
#pragma unroll
  for (int off = 32; off; off >>= 1) v += __shfl_xor(v, off, 64);
  return v;
}

__device__ __forceinline__ float bcast0(float v) {
  return __int_as_float(__builtin_amdgcn_readfirstlane(__float_as_int(v)));
}

// One half-scan of the exp-space linear recurrence. Consumes emissions at
// time index t0 + DIR*n for n = 0..N-1. State is the normalized exp-space
// vector (one element per lane); returns the accumulated log offset.
//   PREMUL=false (forward):  publish a;        matvec; a = s*E
//   PREMUL=true  (backward): publish b*E;      matvec; b = s
// Renorm cadence and pending-r folding identical to the verified kernel:
// r computed at q==3/7 from bcast0(state), applied exactly once via E at the
// next q==0/4, any still-pending r folded into state at the end.
template <int DIR, bool PREMUL>
__device__ __forceinline__ float scan_half(const float* __restrict__ emj,
                                           int t0, int N, int tmax,
                                           const float (&c)[KSTATES],
                                           float& state,
                                           float (&lds)[2][KSTATES], int j) {
  float C = 0.f, r = 1.0f;

  float ring[8];
#pragma unroll
  for (int q = 0; q < 8; ++q) {
    int tq = t0 + DIR * q;
    tq = min(max(tq, 0), tmax);
    ring[q] = emj[(size_t)tq * KSTATES];
  }

  for (int n = 0; n < N; n += 8) {
    float nring[8];
#pragma unroll
    for (int q = 0; q < 8; ++q) {
      int tq = t0 + DIR * (n + 8 + q);
      tq = min(max(tq, 0), tmax);
      nring[q] = emj[(size_t)tq * KSTATES];
    }

#pragma unroll
    for (int q = 0; q < 8; ++q) {
      if (n + q < N) {  // N is wave-uniform -> scalar branch, no divergence
        float E = __expf(ring[q]);
        if (q == 0 || q == 4) {  // apply pending renorm exactly once
          E *= r;
          r = 1.0f;
        }

        float* buf = lds[(n + q) & 1];
        buf[j] = PREMUL ? state * E : state;
        __builtin_amdgcn_wave_barrier();
        const float4* Av = (const float4*)buf;
        float acc0 = 0.f, acc1 = 0.f, acc2 = 0.f, acc3 = 0.f;
#pragma unroll
        for (int p = 0; p < 16; ++p) {
          float4 v = Av[p];
          acc0 = fmaf(v.x, c[4 * p + 0], acc0);
          acc1 = fmaf(v.y, c[4 * p + 1], acc1);
          acc2 = fmaf(v.z, c[4 * p + 2], acc2);
          acc3 = fmaf(v.w, c[4 * p + 3], acc3);
        }
        float s = (acc0 + acc1) + (acc2 + acc3);
        state = PREMUL ? s : s * E;

        if (q == 3 || q == 7) {  // renorm every 4 steps (off critical path)
          float ar = bcast0(state);
          C += __logf(ar);
          r = __builtin_amdgcn_rcpf(ar);
        }
      }
    }

#pragma unroll
    for (int q = 0; q < 8; ++q) ring[q] = nring[q];
  }

  state *= r;  // fold any pending renorm
  return C;
}

// 2 waves/block: wave 0 runs the forward scan to the meeting point m,
// wave 1 runs the backward scan down to m. Z = sum_j alpha_m[j]*beta_m[j]
// (exact for any m), so the sequential critical path halves: ~1023 -> ~512
// steps. 512 blocks x 2 waves = 4 waves/CU (one per SIMD).
__global__ __launch_bounds__(128)
__attribute__((amdgpu_waves_per_eu(1, 1))) void crf_kernel(
    const float* __restrict__ emissions,   // [B, T, K]
    const float* __restrict__ transitions, // [K, K]
    const float* __restrict__ start_trans, // [K]
    const float* __restrict__ end_trans,   // [K]
    const int* __restrict__ labels,        // [B, T]
    const int* __restrict__ sent_len,      // [B]
    float* __restrict__ out,               // scalar
    int T, float inv_B) {
  const int b = blockIdx.x;
  const int tid = threadIdx.x;
  const int wid = tid >> 6;  // 0 = forward wave, 1 = backward wave
  const int j = tid & 63;    // state index == lane
  const int sl = sent_len[b];
  const int tmax = T - 1;

  __shared__ float Sbuf[2][2][KSTATES];  // per-wave double buffer
  __shared__ float Gpart[2];
  __shared__ float Cpart;

  const float* em = emissions + (size_t)b * T * KSTATES;
  const int* lbl = labels + (size_t)b * T;
  const float* emj = em + j;

  // ---- gold score: lane-parallel over time, split across both waves ----
  float g = 0.f;
#pragma unroll 4
  for (int t0 = tid; t0 < T; t0 += 128) {
    if (t0 < sl) {
      int lab = lbl[t0];
      float v = em[(size_t)t0 * KSTATES + lab];
      if (t0 == 0)
        v += start_trans[lab];
      else
        v += transitions[lbl[t0 - 1] * KSTATES + lab];
      if (t0 == sl - 1) v += end_trans[lab];
      g += v;
    }
  }
  float gw = wave_sum64(g);
  if (j == 0) Gpart[wid] = gw;

  const int m = sl >> 1;  // meeting point: fwd ends holding alpha_m

  float state, Coff;
  if (wid == 0) {
    // ---- forward: c[i] = exp(T[i][j]) (column j, coalesced) ----
    float c[KSTATES];
#pragma unroll
    for (int i = 0; i < KSTATES; ++i)
      c[i] = __expf(transitions[i * KSTATES + j]);

    float a0 = start_trans[j] + emj[0];
    float m0 = wave_max64(a0);
    state = __expf(a0 - m0);
    // consume emissions t = 1..m  -> state ~ alpha_m (normalized)
    Coff = m0 + scan_half<1, false>(emj, 1, m, tmax, c, state, Sbuf[0], j);
  } else {
    // ---- backward: c[i] = exp(T[j][i]) (row j; 16KB matrix, L1-resident) ----
    float c[KSTATES];
#pragma unroll
    for (int i = 0; i < KSTATES; ++i)
      c[i] = __expf(transitions[j * KSTATES + i]);

    float b0 = end_trans[j];
    float mb = wave_max64(b0);
    state = __expf(b0 - mb);
    // consume emissions t = sl-1 down to m+1 -> state ~ beta_m (normalized)
    Coff = mb + scan_half<-1, true>(emj, sl - 1, sl - 1 - m, tmax, c, state,
                                    Sbuf[1], j);
  }

  if (wid == 0) {
    Sbuf[0][0][j] = state;  // own-wave buffer reuse after scan: in-order LDS
    if (j == 0) Cpart = Coff;
  }
  __syncthreads();

  if (wid == 1) {
    // Z = sum_j alpha_m[j] * beta_m[j]
    float v = Sbuf[0][0][j] * state;
    float sum = wave_sum64(v);
    float fwd = Cpart + Coff + __logf(sum);
    if (j == 0) atomicAdd(out, (fwd - Gpart[0] - Gpart[1]) * inv_B);
  }
}

extern "C" void kernel_launch(void* const* d_in, const int* in_sizes, int n_in,
                              void* d_out, int out_size, void* d_ws,
                              size_t ws_size, hipStream_t stream) {
  const float* emissions = (const float*)d_in[0];
  const float* transitions = (const float*)d_in[1];
  const float* start_trans = (const float*)d_in[2];
  const float* end_trans = (const float*)d_in[3];
  const int* labels = (const int*)d_in[4];
  const int* sent_len = (const int*)d_in[5];
  float* out = (float*)d_out;

  const int B = in_sizes[5];
  const int T = in_sizes[4] / B;

  hipMemsetAsync(out, 0, sizeof(float), stream);
  crf_kernel<<<B, 128, 0, stream>>>(emissions, transitions, start_trans,
                                    end_trans, labels, sent_len, out, T,
                                    1.0f / (float)B);
}

// Round 2
// 302.416 us; speedup vs baseline: 1.7342x; 1.1826x over previous
//
#include <hip/hip_runtime.h>

#define KSTATES 64

__device__ __forceinline__ float wave_max64(float v) {
#pragma unroll
  for (int off = 32; off; off >>= 1) v = fmaxf(v, __shfl_xor(v, off, 64));
  return v;
}

__device__ __forceinline__ float wave_sum64(float v) {
#pragma unroll
  for (int off = 32; off; off >>= 1) v += __shfl_xor(v, off, 64);
  return v;
}

__device__ __forceinline__ float bcast0(float v) {
  return __int_as_float(__builtin_amdgcn_readfirstlane(__float_as_int(v)));
}

// One half-scan of the exp-space linear recurrence. Consumes emissions at
// time index t0 + DIR*n for n = 0..N-1. State is the normalized exp-space
// vector (one element per lane); returns the accumulated log offset.
//   PREMUL=false (forward):  broadcast a;   matvec; a = s*E
//   PREMUL=true  (backward): broadcast b*E; matvec; b = s
// Matvec broadcast is v_readlane -> SGPR -> v_fmac (SGPR src): pure VALU,
// per-SIMD, no shared-LDS-pipe serialization across the 4 resident waves,
// no 120-cy LDS latency on the critical chain. Summation order (4 chains
// over i mod 4) is bit-identical to the LDS-broadcast version.
template <int DIR, bool PREMUL>
__device__ __forceinline__ float scan_half(const float* __restrict__ emj,
                                           int t0, int N, int tmax,
                                           const float (&c)[KSTATES],
                                           float& state) {
  float C = 0.f, r = 1.0f;

  float ring[8];
#pragma unroll
  for (int q = 0; q < 8; ++q) {
    int tq = t0 + DIR * q;
    tq = min(max(tq, 0), tmax);
    ring[q] = emj[(size_t)tq * KSTATES];
  }

  for (int n = 0; n < N; n += 8) {
    float nring[8];
#pragma unroll
    for (int q = 0; q < 8; ++q) {
      int tq = t0 + DIR * (n + 8 + q);
      tq = min(max(tq, 0), tmax);
      nring[q] = emj[(size_t)tq * KSTATES];
    }

#pragma unroll
    for (int q = 0; q < 8; ++q) {
      if (n + q < N) {  // N is wave-uniform -> scalar branch, no divergence
        float E = __expf(ring[q]);
        if (q == 0 || q == 4) {  // apply pending renorm exactly once
          E *= r;
          r = 1.0f;
        }

        float av = PREMUL ? state * E : state;
        int ai = __float_as_int(av);

        float acc0 = 0.f, acc1 = 0.f, acc2 = 0.f, acc3 = 0.f;
#pragma unroll
        for (int i = 0; i < KSTATES; i += 4) {
          float a0 = __int_as_float(__builtin_amdgcn_readlane(ai, i + 0));
          float a1 = __int_as_float(__builtin_amdgcn_readlane(ai, i + 1));
          float a2 = __int_as_float(__builtin_amdgcn_readlane(ai, i + 2));
          float a3 = __int_as_float(__builtin_amdgcn_readlane(ai, i + 3));
          acc0 = fmaf(a0, c[i + 0], acc0);
          acc1 = fmaf(a1, c[i + 1], acc1);
          acc2 = fmaf(a2, c[i + 2], acc2);
          acc3 = fmaf(a3, c[i + 3], acc3);
        }
        float s = (acc0 + acc1) + (acc2 + acc3);
        state = PREMUL ? s : s * E;

        if (q == 3 || q == 7) {  // renorm every 4 steps (off critical path)
          float ar = bcast0(state);
          C += __logf(ar);
          r = __builtin_amdgcn_rcpf(ar);
        }
      }
    }

#pragma unroll
    for (int q = 0; q < 8; ++q) ring[q] = nring[q];
  }

  state *= r;  // fold any pending renorm
  return C;
}

// 2 waves/block: wave 0 runs the forward scan to the meeting point m,
// wave 1 runs the backward scan down to m. Z = sum_j alpha_m[j]*beta_m[j]
// (exact for any m), so the sequential critical path halves: ~1023 -> ~512
// steps. 512 blocks x 2 waves = 4 waves/CU (one per SIMD), each pure-VALU.
__global__ __launch_bounds__(128)
__attribute__((amdgpu_waves_per_eu(1, 1))) void crf_kernel(
    const float* __restrict__ emissions,   // [B, T, K]
    const float* __restrict__ transitions, // [K, K]
    const float* __restrict__ start_trans, // [K]
    const float* __restrict__ end_trans,   // [K]
    const int* __restrict__ labels,        // [B, T]
    const int* __restrict__ sent_len,      // [B]
    float* __restrict__ out,               // scalar
    int T, float inv_B) {
  const int b = blockIdx.x;
  const int tid = threadIdx.x;
  const int wid = tid >> 6;  // 0 = forward wave, 1 = backward wave
  const int j = tid & 63;    // state index == lane
  const int sl = sent_len[b];
  const int tmax = T - 1;

  __shared__ float Afin[KSTATES];  // alpha_m handoff
  __shared__ float Gpart[2];
  __shared__ float Cpart;

  const float* em = emissions + (size_t)b * T * KSTATES;
  const int* lbl = labels + (size_t)b * T;
  const float* emj = em + j;

  // ---- gold score: lane-parallel over time, split across both waves ----
  float g = 0.f;
#pragma unroll 4
  for (int t0 = tid; t0 < T; t0 += 128) {
    if (t0 < sl) {
      int lab = lbl[t0];
      float v = em[(size_t)t0 * KSTATES + lab];
      if (t0 == 0)
        v += start_trans[lab];
      else
        v += transitions[lbl[t0 - 1] * KSTATES + lab];
      if (t0 == sl - 1) v += end_trans[lab];
      g += v;
    }
  }
  float gw = wave_sum64(g);
  if (j == 0) Gpart[wid] = gw;

  const int m = sl >> 1;  // meeting point: fwd ends holding alpha_m

  float state, Coff;
  if (wid == 0) {
    // ---- forward: c[i] = exp(T[i][j]) (column j, coalesced) ----
    float c[KSTATES];
#pragma unroll
    for (int i = 0; i < KSTATES; ++i)
      c[i] = __expf(transitions[i * KSTATES + j]);

    float a0 = start_trans[j] + emj[0];
    float m0 = wave_max64(a0);
    state = __expf(a0 - m0);
    // consume emissions t = 1..m  -> state ~ alpha_m (normalized)
    Coff = m0 + scan_half<1, false>(emj, 1, m, tmax, c, state);
  } else {
    // ---- backward: c[i] = exp(T[j][i]) (row j; 16KB matrix, L1-resident) ----
    float c[KSTATES];
#pragma unroll
    for (int i = 0; i < KSTATES; ++i)
      c[i] = __expf(transitions[j * KSTATES + i]);

    float b0 = end_trans[j];
    float mb = wave_max64(b0);
    state = __expf(b0 - mb);
    // consume emissions t = sl-1 down to m+1 -> state ~ beta_m (normalized)
    Coff = mb + scan_half<-1, true>(emj, sl - 1, sl - 1 - m, tmax, c, state);
  }

  if (wid == 0) {
    Afin[j] = state;
    if (j == 0) Cpart = Coff;
  }
  __syncthreads();

  if (wid == 1) {
    // Z = sum_j alpha_m[j] * beta_m[j]
    float v = Afin[j] * state;
    float sum = wave_sum64(v);
    float fwd = Cpart + Coff + __logf(sum);
    if (j == 0) atomicAdd(out, (fwd - Gpart[0] - Gpart[1]) * inv_B);
  }
}

extern "C" void kernel_launch(void* const* d_in, const int* in_sizes, int n_in,
                              void* d_out, int out_size, void* d_ws,
                              size_t ws_size, hipStream_t stream) {
  const float* emissions = (const float*)d_in[0];
  const float* transitions = (const float*)d_in[1];
  const float* start_trans = (const float*)d_in[2];
  const float* end_trans = (const float*)d_in[3];
  const int* labels = (const int*)d_in[4];
  const int* sent_len = (const int*)d_in[5];
  float* out = (float*)d_out;

  const int B = in_sizes[5];
  const int T = in_sizes[4] / B;

  hipMemsetAsync(out, 0, sizeof(float), stream);
  crf_kernel<<<B, 128, 0, stream>>>(emissions, transitions, start_trans,
                                    end_trans, labels, sent_len, out, T,
                                    1.0f / (float)B);
}